// Round 7
// baseline (141.705 us; speedup 1.0000x reference)
//
#include <hip/hip_runtime.h>
#include <math.h>

#define NJ 14
#define NE 42            // floats per item per tensor
#define TPB 64           // ONE wave per block -> wave-synchronous LDS, zero barriers
#define SLICE (TPB * NE) // 2688 dwords = 10752 B (ONE buffer, reused for both tensors)

__device__ __forceinline__ float frcp(float x) { return __builtin_amdgcn_rcpf(x); }
__device__ __forceinline__ float frsq(float x) { return __builtin_amdgcn_rsqf(x); }
__device__ __forceinline__ float fsqr(float x) { return __builtin_amdgcn_sqrtf(x); }

// Branchless cyclic Jacobi rotation on symmetric A, accumulating V.
template <int p, int q, int r>
__device__ __forceinline__ void jrot(float A[3][3], float V[3][3]) {
    float apq = A[p][q];
    float apq_s = apq + copysignf(1e-30f, apq);
    float tau = (A[q][q] - A[p][p]) * 0.5f * frcp(apq_s);
    float t = copysignf(frcp(fabsf(tau) + fsqr(1.0f + tau * tau)), tau);
    float c = frsq(1.0f + t * t);
    float s = t * c;
    float app = A[p][p], aqq = A[q][q];
    A[p][p] = app - t * apq;
    A[q][q] = aqq + t * apq;
    A[p][q] = 0.0f;
    A[q][p] = 0.0f;
    float arp = A[r][p], arq = A[r][q];
    A[r][p] = c * arp - s * arq;
    A[p][r] = A[r][p];
    A[r][q] = s * arp + c * arq;
    A[q][r] = A[r][q];
#pragma unroll
    for (int k = 0; k < 3; ++k) {
        float vkp = V[k][p], vkq = V[k][q];
        V[k][p] = c * vkp - s * vkq;
        V[k][q] = s * vkp + c * vkq;
    }
}

// Round 6 was LDS-occupancy-capped: 21.5 KB/block -> 7 blocks/CU, not enough
// waves to hide staging latency (kernel ~41us vs ~14us HBM floor). Round 7:
// ONE 10.75 KB buffer reused for both tensors -> 14 blocks/CU LDS cap.
// Safety of reuse without barriers: 1-wave block; BOTH tensors preloaded to
// registers up front (single latency exposure); __threadfence_block between
// pd readback and gt LDS write pins compiler order, and wave-wide DS
// execution means all lanes' reads retire before the fence does.
__global__ __launch_bounds__(TPB) void pampjpe_kernel(
    const float* __restrict__ pred, const float* __restrict__ gt,
    float* __restrict__ out, int n_items) {
    __shared__ float s[SLICE];

    const int tid = threadIdx.x;  // lane id (wave64)
    const long long blk_base = (long long)blockIdx.x * SLICE;
    const long long total = (long long)n_items * NE;
    const float* pb = pred + blk_base;
    const float* gb = gt + blk_base;

    // ---- preload BOTH tensors into registers (all loads in flight at once) ----
    float4 pr[10], gr[10];
    float2 prt, grt;
    if (blk_base + SLICE <= total) {  // wave-uniform; always true for B=262144
#pragma unroll
        for (int k = 0; k < 10; ++k) {
            int idx = (k * TPB + tid) * 4;
            pr[k] = *(const float4*)(pb + idx);
            gr[k] = *(const float4*)(gb + idx);
        }
        prt = *(const float2*)(pb + 10 * TPB * 4 + tid * 2);
        grt = *(const float2*)(gb + 10 * TPB * 4 + tid * 2);
    } else {  // cold tail path (generic n)
        const long long lim4 = total - 4, lim2 = total - 2;
#pragma unroll
        for (int k = 0; k < 10; ++k) {
            long long g = blk_base + (long long)(k * TPB + tid) * 4;
            g = g > lim4 ? lim4 : g;
            pr[k] = *(const float4*)(pred + g);
            gr[k] = *(const float4*)(gt + g);
        }
        long long g = blk_base + 10 * TPB * 4 + tid * 2;
        g = g > lim2 ? lim2 : g;
        prt = *(const float2*)(pred + g);
        grt = *(const float2*)(gt + g);
    }

    // ---- pred: LDS write (linear) then transposed readback ----
    float pd[NE], gd[NE];
#pragma unroll
    for (int k = 0; k < 10; ++k) *(float4*)(s + (k * TPB + tid) * 4) = pr[k];
    *(float2*)(s + 10 * TPB * 4 + tid * 2) = prt;
#pragma unroll
    for (int e = 0; e < NE; e += 2) {
        float2 v = *(const float2*)(s + tid * NE + e);  // 2 lanes/bank = free
        pd[e] = v.x; pd[e + 1] = v.y;
    }

    // Pin order: no gt write may pass a pd read (cross-lane aliasing the
    // compiler can't see). lgkmcnt(0) here is needed for pd data anyway.
    __threadfence_block();

    // ---- gt: same buffer ----
#pragma unroll
    for (int k = 0; k < 10; ++k) *(float4*)(s + (k * TPB + tid) * 4) = gr[k];
    *(float2*)(s + 10 * TPB * 4 + tid * 2) = grt;
#pragma unroll
    for (int e = 0; e < NE; e += 2) {
        float2 v = *(const float2*)(s + tid * NE + e);
        gd[e] = v.x; gd[e + 1] = v.y;
    }

    const int me = blockIdx.x * TPB + tid;

    // ---- moments ----
    float Sp0 = 0.f, Sp1 = 0.f, Sp2 = 0.f;
    float Sg0 = 0.f, Sg1 = 0.f, Sg2 = 0.f;
    float pp = 0.f;
    float M[3][3] = {{0.f, 0.f, 0.f}, {0.f, 0.f, 0.f}, {0.f, 0.f, 0.f}};
#pragma unroll
    for (int j = 0; j < NJ; ++j) {
        float px = pd[3 * j + 0], py = pd[3 * j + 1], pz = pd[3 * j + 2];
        float gx = gd[3 * j + 0], gy = gd[3 * j + 1], gz = gd[3 * j + 2];
        Sp0 += px; Sp1 += py; Sp2 += pz;
        Sg0 += gx; Sg1 += gy; Sg2 += gz;
        pp += px * px + py * py + pz * pz;
        M[0][0] += px * gx; M[0][1] += px * gy; M[0][2] += px * gz;
        M[1][0] += py * gx; M[1][1] += py * gy; M[1][2] += py * gz;
        M[2][0] += pz * gx; M[2][1] += pz * gy; M[2][2] += pz * gz;
    }
    const float invJ = 1.0f / (float)NJ;
    float mp[3] = {Sp0 * invJ, Sp1 * invJ, Sp2 * invJ};
    float mg[3] = {Sg0 * invJ, Sg1 * invJ, Sg2 * invJ};

    float K[3][3];
#pragma unroll
    for (int i = 0; i < 3; ++i)
#pragma unroll
        for (int j = 0; j < 3; ++j)
            K[i][j] = M[i][j] - (float)NJ * mp[i] * mg[j];
    float var1 = pp - (float)NJ * (mp[0] * mp[0] + mp[1] * mp[1] + mp[2] * mp[2]);
    var1 = fmaxf(var1, 1e-30f);

    // ---- A = K^T K, Jacobi (5 sweeps, branchless) ----
    float A[3][3];
#pragma unroll
    for (int i = 0; i < 3; ++i)
#pragma unroll
        for (int j = 0; j < 3; ++j)
            A[i][j] = K[0][i] * K[0][j] + K[1][i] * K[1][j] + K[2][i] * K[2][j];
    float V[3][3] = {{1.f, 0.f, 0.f}, {0.f, 1.f, 0.f}, {0.f, 0.f, 1.f}};
#pragma unroll
    for (int sweep = 0; sweep < 5; ++sweep) {
        jrot<0, 1, 2>(A, V);
        jrot<0, 2, 1>(A, V);
        jrot<1, 2, 0>(A, V);
    }
    float lam0 = A[0][0], lam1 = A[1][1], lam2 = A[2][2];

#define SWAPCOL(la, lb, a, b)                                     \
    {                                                             \
        float _t;                                                 \
        _t = la; la = lb; lb = _t;                                \
        _t = V[0][a]; V[0][a] = V[0][b]; V[0][b] = _t;            \
        _t = V[1][a]; V[1][a] = V[1][b]; V[1][b] = _t;            \
        _t = V[2][a]; V[2][a] = V[2][b]; V[2][b] = _t;            \
    }
    if (lam0 < lam1) SWAPCOL(lam0, lam1, 0, 1)
    if (lam0 < lam2) SWAPCOL(lam0, lam2, 0, 2)
    if (lam1 < lam2) SWAPCOL(lam1, lam2, 1, 2)
#undef SWAPCOL

    float v0[3] = {V[0][0], V[1][0], V[2][0]};
    float v1[3] = {V[0][1], V[1][1], V[2][1]};
    float v2[3] = {V[0][2], V[1][2], V[2][2]};

    // det(V) = +1
    float cxx = v0[1] * v1[2] - v0[2] * v1[1];
    float cxy = v0[2] * v1[0] - v0[0] * v1[2];
    float cxz = v0[0] * v1[1] - v0[1] * v1[0];
    float detv = cxx * v2[0] + cxy * v2[1] + cxz * v2[2];
    if (detv < 0.f) { v2[0] = -v2[0]; v2[1] = -v2[1]; v2[2] = -v2[2]; }

    // U via K*v + Gram-Schmidt; u3 = u1 x u2 -> det(U)=+1
    float w0[3], w1[3];
#pragma unroll
    for (int i = 0; i < 3; ++i) {
        w0[i] = K[i][0] * v0[0] + K[i][1] * v0[1] + K[i][2] * v0[2];
        w1[i] = K[i][0] * v1[0] + K[i][1] * v1[1] + K[i][2] * v1[2];
    }
    float inv0 = frsq(fmaxf(w0[0] * w0[0] + w0[1] * w0[1] + w0[2] * w0[2], 1e-30f));
    float u1[3] = {w0[0] * inv0, w0[1] * inv0, w0[2] * inv0};
    float d1 = u1[0] * w1[0] + u1[1] * w1[1] + u1[2] * w1[2];
    w1[0] -= d1 * u1[0]; w1[1] -= d1 * u1[1]; w1[2] -= d1 * u1[2];
    float inv1 = frsq(fmaxf(w1[0] * w1[0] + w1[1] * w1[1] + w1[2] * w1[2], 1e-30f));
    float u2[3] = {w1[0] * inv1, w1[1] * inv1, w1[2] * inv1};
    float u3[3] = {u1[1] * u2[2] - u1[2] * u2[1],
                   u1[2] * u2[0] - u1[0] * u2[2],
                   u1[0] * u2[1] - u1[1] * u2[0]};

    // R = V U^T
    float R[3][3];
#pragma unroll
    for (int i = 0; i < 3; ++i) {
        R[i][0] = v0[i] * u1[0] + v1[i] * u2[0] + v2[i] * u3[0];
        R[i][1] = v0[i] * u1[1] + v1[i] * u2[1] + v2[i] * u3[1];
        R[i][2] = v0[i] * u1[2] + v1[i] * u2[2] + v2[i] * u3[2];
    }
    float trRK = 0.f;
#pragma unroll
    for (int i = 0; i < 3; ++i)
#pragma unroll
        for (int j = 0; j < 3; ++j)
            trRK += R[i][j] * K[j][i];
    float scale = trRK * frcp(var1);

    // ---- loss from registers ----
    float acc = 0.f;
#pragma unroll
    for (int j = 0; j < NJ; ++j) {
        float x0 = pd[3 * j + 0] - mp[0];
        float x1 = pd[3 * j + 1] - mp[1];
        float x2 = pd[3 * j + 2] - mp[2];
        float y0 = gd[3 * j + 0] - mg[0];
        float y1 = gd[3 * j + 1] - mg[1];
        float y2 = gd[3 * j + 2] - mg[2];
        float e0 = scale * (R[0][0] * x0 + R[0][1] * x1 + R[0][2] * x2) - y0;
        float e1 = scale * (R[1][0] * x0 + R[1][1] * x1 + R[1][2] * x2) - y1;
        float e2 = scale * (R[2][0] * x0 + R[2][1] * x1 + R[2][2] * x2) - y2;
        acc += fsqr(e0 * e0 + e1 * e1 + e2 * e2);
    }
    if (me < n_items) out[me] = acc * invJ;
}

extern "C" void kernel_launch(void* const* d_in, const int* in_sizes, int n_in,
                              void* d_out, int out_size, void* d_ws, size_t ws_size,
                              hipStream_t stream) {
    const float* pred = (const float*)d_in[0];
    const float* gt = (const float*)d_in[1];
    float* out = (float*)d_out;
    int n_items = in_sizes[0] / NE;  // 262144
    int grid = (n_items + TPB - 1) / TPB;
    pampjpe_kernel<<<grid, TPB, 0, stream>>>(pred, gt, out, n_items);
}

// Round 8
// 140.628 us; speedup vs baseline: 1.0077x; 1.0077x over previous
//
#include <hip/hip_runtime.h>
#include <math.h>

#define NJ 14
#define NE 42            // floats per item per tensor
#define TPB 64           // ONE wave per block -> wave-synchronous LDS, zero barriers
#define SLICE (TPB * NE) // 2688 dwords = 10752 B (ONE buffer, reused for both tensors)

__device__ __forceinline__ float frcp(float x) { return __builtin_amdgcn_rcpf(x); }
__device__ __forceinline__ float frsq(float x) { return __builtin_amdgcn_rsqf(x); }
__device__ __forceinline__ float fsqr(float x) { return __builtin_amdgcn_sqrtf(x); }

// Branchless cyclic Jacobi rotation on symmetric A, accumulating V.
template <int p, int q, int r>
__device__ __forceinline__ void jrot(float A[3][3], float V[3][3]) {
    float apq = A[p][q];
    float apq_s = apq + copysignf(1e-30f, apq);
    float tau = (A[q][q] - A[p][p]) * 0.5f * frcp(apq_s);
    float t = copysignf(frcp(fabsf(tau) + fsqr(1.0f + tau * tau)), tau);
    float c = frsq(1.0f + t * t);
    float s = t * c;
    float app = A[p][p], aqq = A[q][q];
    A[p][p] = app - t * apq;
    A[q][q] = aqq + t * apq;
    A[p][q] = 0.0f;
    A[q][p] = 0.0f;
    float arp = A[r][p], arq = A[r][q];
    A[r][p] = c * arp - s * arq;
    A[p][r] = A[r][p];
    A[r][q] = s * arp + c * arq;
    A[q][r] = A[r][q];
#pragma unroll
    for (int k = 0; k < 3; ++k) {
        float vkp = V[k][p], vkq = V[k][q];
        V[k][p] = c * vkp - s * vkq;
        V[k][q] = s * vkp + c * vkq;
    }
}

// Round 7 structure was right (single latency exposure: both tensors' 22
// loads in flight; 10.75KB LDS -> 14 blocks/CU) but the allocator's DEFAULT
// waves-per-EU heuristic capped VGPRs at 104 and spilled the 84-reg staging
// set (WRITE 83MB). Fix: __launch_bounds__(64, 1) -> min 1 wave/EU -> full
// 512-VGPR budget -> ~160 regs, zero spill. Occupancy stays LDS-bound
// (14 blocks/CU), which is plenty to hide the single HBM exposure.
__global__ __launch_bounds__(TPB, 1) void pampjpe_kernel(
    const float* __restrict__ pred, const float* __restrict__ gt,
    float* __restrict__ out, int n_items) {
    __shared__ float s[SLICE];

    const int tid = threadIdx.x;  // lane id (wave64)
    const long long blk_base = (long long)blockIdx.x * SLICE;
    const long long total = (long long)n_items * NE;
    const float* pb = pred + blk_base;
    const float* gb = gt + blk_base;

    // ---- preload BOTH tensors into registers (all loads in flight at once) ----
    float4 pr[10], gr[10];
    float2 prt, grt;
    if (blk_base + SLICE <= total) {  // wave-uniform; always true for B=262144
#pragma unroll
        for (int k = 0; k < 10; ++k) {
            int idx = (k * TPB + tid) * 4;
            pr[k] = *(const float4*)(pb + idx);
            gr[k] = *(const float4*)(gb + idx);
        }
        prt = *(const float2*)(pb + 10 * TPB * 4 + tid * 2);
        grt = *(const float2*)(gb + 10 * TPB * 4 + tid * 2);
    } else {  // cold tail path (generic n)
        const long long lim4 = total - 4, lim2 = total - 2;
#pragma unroll
        for (int k = 0; k < 10; ++k) {
            long long g = blk_base + (long long)(k * TPB + tid) * 4;
            g = g > lim4 ? lim4 : g;
            pr[k] = *(const float4*)(pred + g);
            gr[k] = *(const float4*)(gt + g);
        }
        long long g = blk_base + 10 * TPB * 4 + tid * 2;
        g = g > lim2 ? lim2 : g;
        prt = *(const float2*)(pred + g);
        grt = *(const float2*)(gt + g);
    }

    // ---- pred: LDS write (linear) then transposed readback ----
    float pd[NE], gd[NE];
#pragma unroll
    for (int k = 0; k < 10; ++k) *(float4*)(s + (k * TPB + tid) * 4) = pr[k];
    *(float2*)(s + 10 * TPB * 4 + tid * 2) = prt;
#pragma unroll
    for (int e = 0; e < NE; e += 2) {
        float2 v = *(const float2*)(s + tid * NE + e);  // 2 lanes/bank = free
        pd[e] = v.x; pd[e + 1] = v.y;
    }

    // Pin order: no gt write may pass a pd read (cross-lane aliasing the
    // compiler can't see). lgkmcnt(0) here is needed for pd data anyway.
    __threadfence_block();

    // ---- gt: same buffer ----
#pragma unroll
    for (int k = 0; k < 10; ++k) *(float4*)(s + (k * TPB + tid) * 4) = gr[k];
    *(float2*)(s + 10 * TPB * 4 + tid * 2) = grt;
#pragma unroll
    for (int e = 0; e < NE; e += 2) {
        float2 v = *(const float2*)(s + tid * NE + e);
        gd[e] = v.x; gd[e + 1] = v.y;
    }

    const int me = blockIdx.x * TPB + tid;

    // ---- moments ----
    float Sp0 = 0.f, Sp1 = 0.f, Sp2 = 0.f;
    float Sg0 = 0.f, Sg1 = 0.f, Sg2 = 0.f;
    float pp = 0.f;
    float M[3][3] = {{0.f, 0.f, 0.f}, {0.f, 0.f, 0.f}, {0.f, 0.f, 0.f}};
#pragma unroll
    for (int j = 0; j < NJ; ++j) {
        float px = pd[3 * j + 0], py = pd[3 * j + 1], pz = pd[3 * j + 2];
        float gx = gd[3 * j + 0], gy = gd[3 * j + 1], gz = gd[3 * j + 2];
        Sp0 += px; Sp1 += py; Sp2 += pz;
        Sg0 += gx; Sg1 += gy; Sg2 += gz;
        pp += px * px + py * py + pz * pz;
        M[0][0] += px * gx; M[0][1] += px * gy; M[0][2] += px * gz;
        M[1][0] += py * gx; M[1][1] += py * gy; M[1][2] += py * gz;
        M[2][0] += pz * gx; M[2][1] += pz * gy; M[2][2] += pz * gz;
    }
    const float invJ = 1.0f / (float)NJ;
    float mp[3] = {Sp0 * invJ, Sp1 * invJ, Sp2 * invJ};
    float mg[3] = {Sg0 * invJ, Sg1 * invJ, Sg2 * invJ};

    float K[3][3];
#pragma unroll
    for (int i = 0; i < 3; ++i)
#pragma unroll
        for (int j = 0; j < 3; ++j)
            K[i][j] = M[i][j] - (float)NJ * mp[i] * mg[j];
    float var1 = pp - (float)NJ * (mp[0] * mp[0] + mp[1] * mp[1] + mp[2] * mp[2]);
    var1 = fmaxf(var1, 1e-30f);

    // ---- A = K^T K, Jacobi (5 sweeps, branchless) ----
    float A[3][3];
#pragma unroll
    for (int i = 0; i < 3; ++i)
#pragma unroll
        for (int j = 0; j < 3; ++j)
            A[i][j] = K[0][i] * K[0][j] + K[1][i] * K[1][j] + K[2][i] * K[2][j];
    float V[3][3] = {{1.f, 0.f, 0.f}, {0.f, 1.f, 0.f}, {0.f, 0.f, 1.f}};
#pragma unroll
    for (int sweep = 0; sweep < 5; ++sweep) {
        jrot<0, 1, 2>(A, V);
        jrot<0, 2, 1>(A, V);
        jrot<1, 2, 0>(A, V);
    }
    float lam0 = A[0][0], lam1 = A[1][1], lam2 = A[2][2];

#define SWAPCOL(la, lb, a, b)                                     \
    {                                                             \
        float _t;                                                 \
        _t = la; la = lb; lb = _t;                                \
        _t = V[0][a]; V[0][a] = V[0][b]; V[0][b] = _t;            \
        _t = V[1][a]; V[1][a] = V[1][b]; V[1][b] = _t;            \
        _t = V[2][a]; V[2][a] = V[2][b]; V[2][b] = _t;            \
    }
    if (lam0 < lam1) SWAPCOL(lam0, lam1, 0, 1)
    if (lam0 < lam2) SWAPCOL(lam0, lam2, 0, 2)
    if (lam1 < lam2) SWAPCOL(lam1, lam2, 1, 2)
#undef SWAPCOL

    float v0[3] = {V[0][0], V[1][0], V[2][0]};
    float v1[3] = {V[0][1], V[1][1], V[2][1]};
    float v2[3] = {V[0][2], V[1][2], V[2][2]};

    // det(V) = +1
    float cxx = v0[1] * v1[2] - v0[2] * v1[1];
    float cxy = v0[2] * v1[0] - v0[0] * v1[2];
    float cxz = v0[0] * v1[1] - v0[1] * v1[0];
    float detv = cxx * v2[0] + cxy * v2[1] + cxz * v2[2];
    if (detv < 0.f) { v2[0] = -v2[0]; v2[1] = -v2[1]; v2[2] = -v2[2]; }

    // U via K*v + Gram-Schmidt; u3 = u1 x u2 -> det(U)=+1
    float w0[3], w1[3];
#pragma unroll
    for (int i = 0; i < 3; ++i) {
        w0[i] = K[i][0] * v0[0] + K[i][1] * v0[1] + K[i][2] * v0[2];
        w1[i] = K[i][0] * v1[0] + K[i][1] * v1[1] + K[i][2] * v1[2];
    }
    float inv0 = frsq(fmaxf(w0[0] * w0[0] + w0[1] * w0[1] + w0[2] * w0[2], 1e-30f));
    float u1[3] = {w0[0] * inv0, w0[1] * inv0, w0[2] * inv0};
    float d1 = u1[0] * w1[0] + u1[1] * w1[1] + u1[2] * w1[2];
    w1[0] -= d1 * u1[0]; w1[1] -= d1 * u1[1]; w1[2] -= d1 * u1[2];
    float inv1 = frsq(fmaxf(w1[0] * w1[0] + w1[1] * w1[1] + w1[2] * w1[2], 1e-30f));
    float u2[3] = {w1[0] * inv1, w1[1] * inv1, w1[2] * inv1};
    float u3[3] = {u1[1] * u2[2] - u1[2] * u2[1],
                   u1[2] * u2[0] - u1[0] * u2[2],
                   u1[0] * u2[1] - u1[1] * u2[0]};

    // R = V U^T
    float R[3][3];
#pragma unroll
    for (int i = 0; i < 3; ++i) {
        R[i][0] = v0[i] * u1[0] + v1[i] * u2[0] + v2[i] * u3[0];
        R[i][1] = v0[i] * u1[1] + v1[i] * u2[1] + v2[i] * u3[1];
        R[i][2] = v0[i] * u1[2] + v1[i] * u2[2] + v2[i] * u3[2];
    }
    float trRK = 0.f;
#pragma unroll
    for (int i = 0; i < 3; ++i)
#pragma unroll
        for (int j = 0; j < 3; ++j)
            trRK += R[i][j] * K[j][i];
    float scale = trRK * frcp(var1);

    // ---- loss from registers ----
    float acc = 0.f;
#pragma unroll
    for (int j = 0; j < NJ; ++j) {
        float x0 = pd[3 * j + 0] - mp[0];
        float x1 = pd[3 * j + 1] - mp[1];
        float x2 = pd[3 * j + 2] - mp[2];
        float y0 = gd[3 * j + 0] - mg[0];
        float y1 = gd[3 * j + 1] - mg[1];
        float y2 = gd[3 * j + 2] - mg[2];
        float e0 = scale * (R[0][0] * x0 + R[0][1] * x1 + R[0][2] * x2) - y0;
        float e1 = scale * (R[1][0] * x0 + R[1][1] * x1 + R[1][2] * x2) - y1;
        float e2 = scale * (R[2][0] * x0 + R[2][1] * x1 + R[2][2] * x2) - y2;
        acc += fsqr(e0 * e0 + e1 * e1 + e2 * e2);
    }
    if (me < n_items) out[me] = acc * invJ;
}

extern "C" void kernel_launch(void* const* d_in, const int* in_sizes, int n_in,
                              void* d_out, int out_size, void* d_ws, size_t ws_size,
                              hipStream_t stream) {
    const float* pred = (const float*)d_in[0];
    const float* gt = (const float*)d_in[1];
    float* out = (float*)d_out;
    int n_items = in_sizes[0] / NE;  // 262144
    int grid = (n_items + TPB - 1) / TPB;
    pampjpe_kernel<<<grid, TPB, 0, stream>>>(pred, gt, out, n_items);
}

// Round 9
// 105.001 us; speedup vs baseline: 1.3496x; 1.3393x over previous
//
#include <hip/hip_runtime.h>
#include <math.h>
#include <stdint.h>

#define NJ 14
#define NE 42            // floats per item per tensor
#define TPB 64           // ONE wave per block -> wave-synchronous, zero barriers
#define SLICE (TPB * NE) // 2688 dwords = 10752 B, ONE buffer reused for both tensors

__device__ __forceinline__ float frcp(float x) { return __builtin_amdgcn_rcpf(x); }
__device__ __forceinline__ float frsq(float x) { return __builtin_amdgcn_rsqf(x); }
__device__ __forceinline__ float fsqr(float x) { return __builtin_amdgcn_sqrtf(x); }

typedef uint32_t u32_as1 __attribute__((address_space(1)));
typedef uint32_t u32_as3 __attribute__((address_space(3)));

// HBM -> LDS DMA: per-lane global address, wave-uniform LDS base + lane*size.
// Staging data never touches VGPRs (rounds 7/8: 84 staging regs spilled at the
// compiler's ~104-VGPR ceiling -> 83 MB scratch traffic; launch_bounds cannot
// raise that ceiling, only lower it).
__device__ __forceinline__ void dma16(const float* g, const float* l) {
    __builtin_amdgcn_global_load_lds((const u32_as1*)(uintptr_t)g,
                                     (u32_as3*)(uintptr_t)l, 16, 0, 0);
}
__device__ __forceinline__ void dma4(const float* g, const float* l) {
    __builtin_amdgcn_global_load_lds((const u32_as1*)(uintptr_t)g,
                                     (u32_as3*)(uintptr_t)l, 4, 0, 0);
}

// Branchless cyclic Jacobi rotation on symmetric A, accumulating V.
template <int p, int q, int r>
__device__ __forceinline__ void jrot(float A[3][3], float V[3][3]) {
    float apq = A[p][q];
    float apq_s = apq + copysignf(1e-30f, apq);
    float tau = (A[q][q] - A[p][p]) * 0.5f * frcp(apq_s);
    float t = copysignf(frcp(fabsf(tau) + fsqr(1.0f + tau * tau)), tau);
    float c = frsq(1.0f + t * t);
    float s = t * c;
    float app = A[p][p], aqq = A[q][q];
    A[p][p] = app - t * apq;
    A[q][q] = aqq + t * apq;
    A[p][q] = 0.0f;
    A[q][p] = 0.0f;
    float arp = A[r][p], arq = A[r][q];
    A[r][p] = c * arp - s * arq;
    A[p][r] = A[r][p];
    A[r][q] = s * arp + c * arq;
    A[q][r] = A[r][q];
#pragma unroll
    for (int k = 0; k < 3; ++k) {
        float vkp = V[k][p], vkq = V[k][q];
        V[k][p] = c * vkp - s * vkq;
        V[k][q] = s * vkp + c * vkq;
    }
}

__global__ __launch_bounds__(TPB) void pampjpe_kernel(
    const float* __restrict__ pred, const float* __restrict__ gt,
    float* __restrict__ out, int n_items) {
    __shared__ float s[SLICE];

    const int tid = threadIdx.x;  // lane id (wave64)
    const long long blk_base = (long long)blockIdx.x * SLICE;  // dword index
    const long long total = (long long)n_items * NE;
    const long long lim4 = total - 4;
    const long long lim1 = total - 1;

    // ---- stage pred via DMA (12 ops, all in flight, zero staging VGPRs) ----
#pragma unroll
    for (int k = 0; k < 10; ++k) {
        long long g = blk_base + k * (TPB * 4) + (long long)tid * 4;
        g = g > lim4 ? lim4 : g;  // OOB lanes land on clamped data; their items unused
        dma16(pred + g, s + k * (TPB * 4));
    }
#pragma unroll
    for (int t = 0; t < 2; ++t) {
        long long g = blk_base + 10 * (TPB * 4) + t * TPB + tid;
        g = g > lim1 ? lim1 : g;
        dma4(pred + g, s + 10 * (TPB * 4) + t * TPB);
    }
    __builtin_amdgcn_s_waitcnt(0x0F70);  // vmcnt(0): DMA stores visible in LDS

    // ---- transposed readback of pred ----
    float pd[NE], gd[NE];
#pragma unroll
    for (int e = 0; e < NE; e += 2) {
        float2 v = *(const float2*)(s + tid * NE + e);  // 2 lanes/bank = free
        pd[e] = v.x; pd[e + 1] = v.y;
    }
    // All pd reads must retire before gt DMA overwrites the buffer.
    __builtin_amdgcn_s_waitcnt(0xC07F);  // lgkmcnt(0)
    __threadfence_block();               // compiler-level LDS ordering pin

    // ---- stage gt into the SAME buffer ----
#pragma unroll
    for (int k = 0; k < 10; ++k) {
        long long g = blk_base + k * (TPB * 4) + (long long)tid * 4;
        g = g > lim4 ? lim4 : g;
        dma16(gt + g, s + k * (TPB * 4));
    }
#pragma unroll
    for (int t = 0; t < 2; ++t) {
        long long g = blk_base + 10 * (TPB * 4) + t * TPB + tid;
        g = g > lim1 ? lim1 : g;
        dma4(gt + g, s + 10 * (TPB * 4) + t * TPB);
    }
    __builtin_amdgcn_s_waitcnt(0x0F70);  // vmcnt(0)

#pragma unroll
    for (int e = 0; e < NE; e += 2) {
        float2 v = *(const float2*)(s + tid * NE + e);
        gd[e] = v.x; gd[e + 1] = v.y;
    }

    const int me = blockIdx.x * TPB + tid;

    // ---- moments ----
    float Sp0 = 0.f, Sp1 = 0.f, Sp2 = 0.f;
    float Sg0 = 0.f, Sg1 = 0.f, Sg2 = 0.f;
    float pp = 0.f;
    float M[3][3] = {{0.f, 0.f, 0.f}, {0.f, 0.f, 0.f}, {0.f, 0.f, 0.f}};
#pragma unroll
    for (int j = 0; j < NJ; ++j) {
        float px = pd[3 * j + 0], py = pd[3 * j + 1], pz = pd[3 * j + 2];
        float gx = gd[3 * j + 0], gy = gd[3 * j + 1], gz = gd[3 * j + 2];
        Sp0 += px; Sp1 += py; Sp2 += pz;
        Sg0 += gx; Sg1 += gy; Sg2 += gz;
        pp += px * px + py * py + pz * pz;
        M[0][0] += px * gx; M[0][1] += px * gy; M[0][2] += px * gz;
        M[1][0] += py * gx; M[1][1] += py * gy; M[1][2] += py * gz;
        M[2][0] += pz * gx; M[2][1] += pz * gy; M[2][2] += pz * gz;
    }
    const float invJ = 1.0f / (float)NJ;
    float mp[3] = {Sp0 * invJ, Sp1 * invJ, Sp2 * invJ};
    float mg[3] = {Sg0 * invJ, Sg1 * invJ, Sg2 * invJ};

    float K[3][3];
#pragma unroll
    for (int i = 0; i < 3; ++i)
#pragma unroll
        for (int j = 0; j < 3; ++j)
            K[i][j] = M[i][j] - (float)NJ * mp[i] * mg[j];
    float var1 = pp - (float)NJ * (mp[0] * mp[0] + mp[1] * mp[1] + mp[2] * mp[2]);
    var1 = fmaxf(var1, 1e-30f);

    // ---- A = K^T K, Jacobi (5 sweeps, branchless) ----
    float A[3][3];
#pragma unroll
    for (int i = 0; i < 3; ++i)
#pragma unroll
        for (int j = 0; j < 3; ++j)
            A[i][j] = K[0][i] * K[0][j] + K[1][i] * K[1][j] + K[2][i] * K[2][j];
    float V[3][3] = {{1.f, 0.f, 0.f}, {0.f, 1.f, 0.f}, {0.f, 0.f, 1.f}};
#pragma unroll
    for (int sweep = 0; sweep < 5; ++sweep) {
        jrot<0, 1, 2>(A, V);
        jrot<0, 2, 1>(A, V);
        jrot<1, 2, 0>(A, V);
    }
    float lam0 = A[0][0], lam1 = A[1][1], lam2 = A[2][2];

#define SWAPCOL(la, lb, a, b)                                     \
    {                                                             \
        float _t;                                                 \
        _t = la; la = lb; lb = _t;                                \
        _t = V[0][a]; V[0][a] = V[0][b]; V[0][b] = _t;            \
        _t = V[1][a]; V[1][a] = V[1][b]; V[1][b] = _t;            \
        _t = V[2][a]; V[2][a] = V[2][b]; V[2][b] = _t;            \
    }
    if (lam0 < lam1) SWAPCOL(lam0, lam1, 0, 1)
    if (lam0 < lam2) SWAPCOL(lam0, lam2, 0, 2)
    if (lam1 < lam2) SWAPCOL(lam1, lam2, 1, 2)
#undef SWAPCOL

    float v0[3] = {V[0][0], V[1][0], V[2][0]};
    float v1[3] = {V[0][1], V[1][1], V[2][1]};
    float v2[3] = {V[0][2], V[1][2], V[2][2]};

    // det(V) = +1
    float cxx = v0[1] * v1[2] - v0[2] * v1[1];
    float cxy = v0[2] * v1[0] - v0[0] * v1[2];
    float cxz = v0[0] * v1[1] - v0[1] * v1[0];
    float detv = cxx * v2[0] + cxy * v2[1] + cxz * v2[2];
    if (detv < 0.f) { v2[0] = -v2[0]; v2[1] = -v2[1]; v2[2] = -v2[2]; }

    // U via K*v + Gram-Schmidt; u3 = u1 x u2 -> det(U)=+1
    float w0[3], w1[3];
#pragma unroll
    for (int i = 0; i < 3; ++i) {
        w0[i] = K[i][0] * v0[0] + K[i][1] * v0[1] + K[i][2] * v0[2];
        w1[i] = K[i][0] * v1[0] + K[i][1] * v1[1] + K[i][2] * v1[2];
    }
    float inv0 = frsq(fmaxf(w0[0] * w0[0] + w0[1] * w0[1] + w0[2] * w0[2], 1e-30f));
    float u1[3] = {w0[0] * inv0, w0[1] * inv0, w0[2] * inv0};
    float d1 = u1[0] * w1[0] + u1[1] * w1[1] + u1[2] * w1[2];
    w1[0] -= d1 * u1[0]; w1[1] -= d1 * u1[1]; w1[2] -= d1 * u1[2];
    float inv1 = frsq(fmaxf(w1[0] * w1[0] + w1[1] * w1[1] + w1[2] * w1[2], 1e-30f));
    float u2[3] = {w1[0] * inv1, w1[1] * inv1, w1[2] * inv1};
    float u3[3] = {u1[1] * u2[2] - u1[2] * u2[1],
                   u1[2] * u2[0] - u1[0] * u2[2],
                   u1[0] * u2[1] - u1[1] * u2[0]};

    // R = V U^T
    float R[3][3];
#pragma unroll
    for (int i = 0; i < 3; ++i) {
        R[i][0] = v0[i] * u1[0] + v1[i] * u2[0] + v2[i] * u3[0];
        R[i][1] = v0[i] * u1[1] + v1[i] * u2[1] + v2[i] * u3[1];
        R[i][2] = v0[i] * u1[2] + v1[i] * u2[2] + v2[i] * u3[2];
    }
    float trRK = 0.f;
#pragma unroll
    for (int i = 0; i < 3; ++i)
#pragma unroll
        for (int j = 0; j < 3; ++j)
            trRK += R[i][j] * K[j][i];
    float scale = trRK * frcp(var1);

    // ---- loss ----
    float acc = 0.f;
#pragma unroll
    for (int j = 0; j < NJ; ++j) {
        float x0 = pd[3 * j + 0] - mp[0];
        float x1 = pd[3 * j + 1] - mp[1];
        float x2 = pd[3 * j + 2] - mp[2];
        float y0 = gd[3 * j + 0] - mg[0];
        float y1 = gd[3 * j + 1] - mg[1];
        float y2 = gd[3 * j + 2] - mg[2];
        float e0 = scale * (R[0][0] * x0 + R[0][1] * x1 + R[0][2] * x2) - y0;
        float e1 = scale * (R[1][0] * x0 + R[1][1] * x1 + R[1][2] * x2) - y1;
        float e2 = scale * (R[2][0] * x0 + R[2][1] * x1 + R[2][2] * x2) - y2;
        acc += fsqr(e0 * e0 + e1 * e1 + e2 * e2);
    }
    if (me < n_items) out[me] = acc * invJ;
}

extern "C" void kernel_launch(void* const* d_in, const int* in_sizes, int n_in,
                              void* d_out, int out_size, void* d_ws, size_t ws_size,
                              hipStream_t stream) {
    const float* pred = (const float*)d_in[0];
    const float* gt = (const float*)d_in[1];
    float* out = (float*)d_out;
    int n_items = in_sizes[0] / NE;  // 262144
    int grid = (n_items + TPB - 1) / TPB;
    pampjpe_kernel<<<grid, TPB, 0, stream>>>(pred, gt, out, n_items);
}